// Round 2
// baseline (972.299 us; speedup 1.0000x reference)
//
#include <hip/hip_runtime.h>
#include <hip/hip_bf16.h>
#include <math.h>

#define WINDOW 4
#define NNODES 50000
#define NEDGES 400000
#define DIM 128
#define BM 64

// dst-binning geometry: bucket = dst >> 6 (64 dsts per bucket)
#define RSH 6
#define RBK 64
#define NBUK ((NNODES + RBK - 1) / RBK)        // 782

typedef short bf16x8 __attribute__((ext_vector_type(8)));
typedef float f32x4  __attribute__((ext_vector_type(4)));

__device__ __forceinline__ float eluf(float x) {
    return x > 0.0f ? x : expm1f(x);
}
__device__ __forceinline__ float bf16_lo(unsigned int v) {
    return __uint_as_float(v << 16);
}
__device__ __forceinline__ float bf16_hi(unsigned int v) {
    return __uint_as_float(v & 0xffff0000u);
}
__device__ __forceinline__ unsigned short f2bf(float f) {
    __hip_bfloat16 h = __float2bfloat16(f);   // RNE
    return *(unsigned short*)&h;
}

// ---- prep: zero bcnt/bcur + cast/transpose W0,W1 -> wt[nb][2][128][128] ----
__global__ __launch_bounds__(256) void prep_kernel(
    const float* __restrict__ W0, const float* __restrict__ W1,
    unsigned short* __restrict__ wt, int* __restrict__ bcnt,
    int* __restrict__ bcur, int nb)
{
    int i = blockIdx.x * 256 + threadIdx.x;
    int ncast = nb * 2 * DIM * DIM;            // nb*32768
    if (i < ncast) {
        int w   = i >> 15;
        int rem = i & 32767;
        int m   = rem >> 14;                   // 0:W0 1:W1
        int j   = rem & 16383;
        int n   = j >> 7, k = j & 127;
        const float* Ws = (m ? W1 : W0) + (size_t)w * DIM * DIM;
        wt[i] = f2bf(Ws[k * DIM + n]);         // wt[(w*2+m)*16384 + n*128 + k]
    }
    if (i < nb * NBUK) { bcnt[i] = 0; bcur[i] = 0; }
}

// ---- bhist: bucket-level histogram (782 hot counters per window) ----
__global__ __launch_bounds__(256) void bhist_kernel(
    const int* __restrict__ ei, int* __restrict__ bcnt)
{
    int e = blockIdx.x * 256 + threadIdx.x;
    int w = blockIdx.y;
    if (e < NEDGES) {
        int d = ei[(size_t)w * 2 * NEDGES + NEDGES + e];
        atomicAdd(&bcnt[w * NBUK + (d >> RSH)], 1);
    }
}

// ---- bscan: exclusive scan of 782 bucket counts (one block per window) ----
__global__ __launch_bounds__(1024) void bscan_kernel(
    const int* __restrict__ bcnt, int* __restrict__ bbase)
{
    const int w = blockIdx.x;
    const int t = threadIdx.x;
    __shared__ int s[1024];
    int orig = (t < NBUK) ? bcnt[w * NBUK + t] : 0;
    s[t] = orig;
    __syncthreads();
    for (int off = 1; off < 1024; off <<= 1) {
        int v = (t >= off) ? s[t - off] : 0;
        __syncthreads();
        s[t] += v;
        __syncthreads();
    }
    if (t < NBUK) bbase[w * (NBUK + 1) + t] = s[t] - orig;     // exclusive
    if (t == NBUK - 1) bbase[w * (NBUK + 1) + NBUK] = s[t];    // total == NEDGES
}

// ---- bucket_p1: append (src|dlo, weight) into bucket region (clustered writes) ----
__global__ __launch_bounds__(256) void bucket_p1(
    const int* __restrict__ ei, const float* __restrict__ ew,
    const int* __restrict__ bbase, int* __restrict__ bcur,
    int2* __restrict__ stage)
{
    int e = blockIdx.x * 256 + threadIdx.x;
    int w = blockIdx.y;
    if (e >= NEDGES) return;
    const int* eiw = ei + (size_t)w * 2 * NEDGES;
    int d = eiw[NEDGES + e];
    int s = eiw[e];
    int b = d >> RSH;
    int pos = bbase[w * (NBUK + 1) + b] + atomicAdd(&bcur[w * NBUK + b], 1);
    stage[(size_t)w * NEDGES + pos] =
        make_int2(s | ((d & (RBK - 1)) << 16),
                  __float_as_int(ew[(size_t)w * NEDGES + e]));
}

// ---- bucket_p2: per-bucket local sort -> offs[dst] + dst-sorted srcw ----
// One block per (bucket, window). ~512 edges/bucket, dense 4KB output region.
__global__ __launch_bounds__(256) void bucket_p2(
    const int2* __restrict__ stage, const int* __restrict__ bbase,
    int* __restrict__ offs, int2* __restrict__ srcw)
{
    const int b = blockIdx.x, w = blockIdx.y;
    const int t = threadIdx.x;
    __shared__ int lh[RBK];
    const int base = bbase[w * (NBUK + 1) + b];
    const int n    = bbase[w * (NBUK + 1) + b + 1] - base;
    if (t < RBK) lh[t] = 0;
    __syncthreads();
    const int2* st = stage + (size_t)w * NEDGES;
    for (int i = t; i < n; i += 256)
        atomicAdd(&lh[(st[base + i].x >> 16) & (RBK - 1)], 1);
    __syncthreads();
    if (t < RBK) {                              // threads 0..63 = wave 0
        int v = lh[t];
        int incl = v;
        #pragma unroll
        for (int off = 1; off < 64; off <<= 1) {
            int u = __shfl_up(incl, off, 64);
            if (t >= off) incl += u;
        }
        int excl = base + incl - v;             // absolute exclusive prefix
        int idx = b * RBK + t;
        if (idx <= NNODES) offs[(size_t)w * (NNODES + 1) + idx] = excl;
        lh[t] = excl;                           // absolute cursor for scatter
    }
    __syncthreads();
    for (int i = t; i < n; i += 256) {
        int2 e = st[base + i];
        int pos = atomicAdd(&lh[(e.x >> 16) & (RBK - 1)], 1);
        srcw[(size_t)w * NEDGES + pos] = make_int2(e.x & 0xffff, e.y);
    }
}

// ---- MFMA GEMM (batched): C_bf16[w] = A'[w] @ W[w], A' = elu(A+bias) if bias ----
__global__ __launch_bounds__(256) void gemm_mfma(
    const void* __restrict__ Avoid, size_t a_stride,        // elements per window
    const unsigned short* __restrict__ WtG, size_t wt_stride,
    const float* __restrict__ bias,                          // null or stride DIM
    unsigned short* __restrict__ C,                          // stride N*DIM
    int a_bf16)
{
    __shared__ unsigned short As[BM][136];
    __shared__ unsigned short Bs[DIM][136];
    const int t  = threadIdx.x;
    const int r0 = blockIdx.x * BM;
    const int w  = blockIdx.y;
    const unsigned short* Wt = WtG + (size_t)w * wt_stride;
    unsigned short* Cw = C + (size_t)w * NNODES * DIM;

    if (a_bf16) {
        const unsigned short* A = (const unsigned short*)Avoid + (size_t)w * a_stride;
        const float* bs = bias + (size_t)w * DIM;
        #pragma unroll
        for (int l = 0; l < 4; ++l) {
            int idx = t + l * 256;             // 1024 uint4 = 64x128 bf16
            int row = idx >> 4, c8 = (idx & 15) << 3;
            int gr  = r0 + row;
            uint4 v = make_uint4(0, 0, 0, 0);
            if (gr < NNODES) v = *(const uint4*)(A + (size_t)gr * DIM + c8);
            union { uint4 u; unsigned short s[8]; } in, ot;
            in.u = v;
            #pragma unroll
            for (int j = 0; j < 8; ++j) {
                float f = __uint_as_float((unsigned int)in.s[j] << 16);
                ot.s[j] = f2bf(eluf(f + bs[c8 + j]));
            }
            *(uint4*)&As[row][c8] = ot.u;
        }
    } else {
        const float* A = (const float*)Avoid + (size_t)w * a_stride;
        #pragma unroll
        for (int l = 0; l < 8; ++l) {
            int idx = t + l * 256;             // 2048 float4 = 64x128 fp32
            int row = idx >> 5, c4 = (idx & 31) << 2;
            int gr  = r0 + row;
            float4 v = make_float4(0.f, 0.f, 0.f, 0.f);
            if (gr < NNODES) v = *(const float4*)(A + (size_t)gr * DIM + c4);
            union { uint2 u; unsigned short s[4]; } ot;
            ot.s[0] = f2bf(v.x); ot.s[1] = f2bf(v.y);
            ot.s[2] = f2bf(v.z); ot.s[3] = f2bf(v.w);
            *(uint2*)&As[row][c4] = ot.u;
        }
    }
    // full W^T: 128x128 bf16 = 2048 uint4 chunks
    #pragma unroll
    for (int l = 0; l < 8; ++l) {
        int idx = t + l * 256;
        int n = idx >> 4, k8 = (idx & 15) << 3;
        *(uint4*)&Bs[n][k8] = *(const uint4*)(Wt + (size_t)n * DIM + k8);
    }
    __syncthreads();

    const int lane = t & 63, wv = t >> 6;
    const int mr = lane & 15, quad = lane >> 4;

    f32x4 acc[8];
    #pragma unroll
    for (int c = 0; c < 8; ++c) acc[c] = (f32x4){0.f, 0.f, 0.f, 0.f};

    const unsigned short* aptr = &As[wv * 16 + mr][quad * 8];
    #pragma unroll
    for (int kc = 0; kc < DIM; kc += 32) {
        bf16x8 a = *(const bf16x8*)(aptr + kc);
        #pragma unroll
        for (int c = 0; c < 8; ++c) {
            bf16x8 b = *(const bf16x8*)(&Bs[c * 16 + mr][quad * 8 + kc]);
            acc[c] = __builtin_amdgcn_mfma_f32_16x16x32_bf16(a, b, acc[c], 0, 0, 0);
        }
    }
    // Epilogue: bounce C tile through LDS (reuse As) -> coalesced uint4 stores
    __syncthreads();
    const int lr0 = wv * 16 + quad * 4;
    #pragma unroll
    for (int c = 0; c < 8; ++c) {
        int col = c * 16 + mr;
        #pragma unroll
        for (int r = 0; r < 4; ++r)
            As[lr0 + r][col] = f2bf(acc[c][r]);   // C/D: col=lane&15, row=quad*4+r
    }
    __syncthreads();
    #pragma unroll
    for (int l = 0; l < 4; ++l) {
        int idx = t + l * 256;                 // 1024 = 64 rows x 16 chunks
        int row = idx >> 4, c8 = (idx & 15) << 3;
        int gr = r0 + row;
        if (gr < NNODES)
            *(uint4*)(Cw + (size_t)gr * DIM + c8) = *(const uint4*)&As[row][c8];
    }
}

// ---- gather_agg (batched): one wave per dst, int2 edge stream, 4-wide ILP ----
// mode 0: agg_bf16[w][dst] = sum.  mode 1: out_f32[w][dst] = elu(sum + bias).
__global__ __launch_bounds__(256) void gather_agg(
    const unsigned short* __restrict__ h,
    const int*  __restrict__ offs,
    const int2* __restrict__ srcw,
    const float* __restrict__ bias,
    void* __restrict__ outp,
    int mode)
{
    const int w = blockIdx.y;
    const unsigned short* hw = h + (size_t)w * NNODES * DIM;
    const int*  ow = offs + (size_t)w * (NNODES + 1);
    const int2* sw = srcw + (size_t)w * NEDGES;
    int wid  = (blockIdx.x * 256 + threadIdx.x) >> 6;
    int lane = threadIdx.x & 63;
    if (wid >= NNODES) return;
    int beg = ow[wid], end = ow[wid + 1];
    const int d0 = lane * 2;
    float ax = 0.f, ay = 0.f;

    int e = beg;
    for (; e + 4 <= end; e += 4) {
        int2 p0 = sw[e],     p1 = sw[e + 1];
        int2 p2 = sw[e + 2], p3 = sw[e + 3];
        unsigned int v0 = *(const unsigned int*)(hw + (size_t)p0.x * DIM + d0);
        unsigned int v1 = *(const unsigned int*)(hw + (size_t)p1.x * DIM + d0);
        unsigned int v2 = *(const unsigned int*)(hw + (size_t)p2.x * DIM + d0);
        unsigned int v3 = *(const unsigned int*)(hw + (size_t)p3.x * DIM + d0);
        float w0 = __int_as_float(p0.y), w1 = __int_as_float(p1.y);
        float w2 = __int_as_float(p2.y), w3 = __int_as_float(p3.y);
        ax += w0 * bf16_lo(v0); ay += w0 * bf16_hi(v0);
        ax += w1 * bf16_lo(v1); ay += w1 * bf16_hi(v1);
        ax += w2 * bf16_lo(v2); ay += w2 * bf16_hi(v2);
        ax += w3 * bf16_lo(v3); ay += w3 * bf16_hi(v3);
    }
    for (; e < end; ++e) {
        int2 p = sw[e];
        float wf = __int_as_float(p.y);
        unsigned int v = *(const unsigned int*)(hw + (size_t)p.x * DIM + d0);
        ax += wf * bf16_lo(v); ay += wf * bf16_hi(v);
    }

    if (mode == 0) {
        unsigned int pk = (unsigned int)f2bf(ax) | ((unsigned int)f2bf(ay) << 16);
        *((unsigned int*)outp + (size_t)w * NNODES * (DIM / 2)
                              + (size_t)wid * (DIM / 2) + lane) = pk;
    } else {
        const float* bs = bias + (size_t)w * DIM;
        float2 r;
        r.x = eluf(ax + bs[d0 + 0]);
        r.y = eluf(ay + bs[d0 + 1]);
        *(float2*)((float*)outp + (size_t)w * NNODES * DIM + (size_t)wid * DIM + d0) = r;
    }
}

extern "C" void kernel_launch(void* const* d_in, const int* in_sizes, int n_in,
                              void* d_out, int out_size, void* d_ws, size_t ws_size,
                              hipStream_t stream) {
    const float* x           = (const float*)d_in[0];
    const int*   edge_index  = (const int*)  d_in[1];
    const float* edge_weight = (const float*)d_in[2];
    const float* W0          = (const float*)d_in[3];
    const float* b0          = (const float*)d_in[4];
    const float* W1          = (const float*)d_in[5];
    const float* b1          = (const float*)d_in[6];
    float*       out         = (float*)d_out;

    const size_t ND = (size_t)NNODES * DIM;

    // Workspace per batched-window: h + agg (bf16) + wt + srcw + offs + bucket meta
    auto need = [&](int nb) -> size_t {
        return (size_t)nb * (ND * 2 + ND * 2 + 2 * DIM * DIM * 2
                             + (size_t)NEDGES * 8
                             + (size_t)(NNODES + 1) * 4
                             + (size_t)NBUK * 4 * 2 + (size_t)(NBUK + 1) * 4);
    };
    int nb = WINDOW;
    while (nb > 1 && need(nb) > ws_size) nb >>= 1;

    char* p = (char*)d_ws;
    unsigned short* h_buf   = (unsigned short*)p;  p += (size_t)nb * ND * 2;
    unsigned short* agg_buf = (unsigned short*)p;  p += (size_t)nb * ND * 2;
    unsigned short* wt      = (unsigned short*)p;  p += (size_t)nb * 2 * DIM * DIM * 2;
    int2*           srcw    = (int2*)p;            p += (size_t)nb * NEDGES * 8;
    int*            offs    = (int*)p;             p += (size_t)nb * (NNODES + 1) * 4;
    int*            bcnt    = (int*)p;             p += (size_t)nb * NBUK * 4;
    int*            bcur    = (int*)p;             p += (size_t)nb * NBUK * 4;
    int*            bbase   = (int*)p;             p += (size_t)nb * (NBUK + 1) * 4;
    int2*           stage   = (int2*)h_buf;        // reuse h_buf before gemm hop 1

    const dim3 eg((NEDGES + 255) / 256, nb);          // edge-parallel
    const dim3 gg((NNODES + BM - 1) / BM, nb);        // gemm tiles
    const dim3 ag((NNODES * 64 + 255) / 256, nb);     // one wave per dst
    const dim3 bg(NBUK, nb);                          // per-bucket pass
    const int  prep_grid = (nb * 2 * DIM * DIM + 255) / 256;

    for (int w0 = 0; w0 < WINDOW; w0 += nb) {
        const float* W0g = W0 + (size_t)w0 * DIM * DIM;
        const float* W1g = W1 + (size_t)w0 * DIM * DIM;
        const int*   eig = edge_index  + (size_t)w0 * 2 * NEDGES;
        const float* ewg = edge_weight + (size_t)w0 * NEDGES;

        prep_kernel <<<prep_grid, 256, 0, stream>>>(W0g, W1g, wt, bcnt, bcur, nb);
        bhist_kernel<<<eg, 256, 0, stream>>>(eig, bcnt);
        bscan_kernel<<<nb, 1024, 0, stream>>>(bcnt, bbase);
        bucket_p1   <<<eg, 256, 0, stream>>>(eig, ewg, bbase, bcur, stage);
        bucket_p2   <<<bg, 256, 0, stream>>>(stage, bbase, offs, srcw);

        // hop 1: h = x @ W0 ; agg = gather(h)   (gemm overwrites stage == h_buf)
        gemm_mfma <<<gg, 256, 0, stream>>>(x + (size_t)w0 * ND, ND,
                                           wt, 2 * DIM * DIM, nullptr, h_buf, 0);
        gather_agg<<<ag, 256, 0, stream>>>(h_buf, offs, srcw, nullptr, agg_buf, 0);
        // hop 2: h = elu(agg+b0) @ W1 ; out = elu(gather(h) + b1)
        gemm_mfma <<<gg, 256, 0, stream>>>(agg_buf, ND,
                                           wt + DIM * DIM, 2 * DIM * DIM,
                                           b0 + (size_t)w0 * DIM, h_buf, 1);
        gather_agg<<<ag, 256, 0, stream>>>(h_buf, offs, srcw,
                                           b1 + (size_t)w0 * DIM,
                                           out + (size_t)w0 * ND, 1);
    }
}

// Round 3
// 484.546 us; speedup vs baseline: 2.0066x; 2.0066x over previous
//
#include <hip/hip_runtime.h>
#include <hip/hip_bf16.h>
#include <math.h>

#define WINDOW 4
#define NNODES 50000
#define NEDGES 400000
#define DIM 128
#define BM 64

// multi-split geometry: coarse bucket = dst >> 9 (512 dsts per bucket)
#define BSH 9
#define BSZ 512
#define NB2 ((NNODES + BSZ - 1) / BSZ)         // 98 buckets
#define EPB 4096                               // edges per p1/bhist block
#define P1B ((NEDGES + EPB - 1) / EPB)         // 98 blocks per window

typedef short bf16x8 __attribute__((ext_vector_type(8)));
typedef float f32x4  __attribute__((ext_vector_type(4)));

__device__ __forceinline__ float eluf(float x) {
    return x > 0.0f ? x : expm1f(x);
}
__device__ __forceinline__ float bf16_lo(unsigned int v) {
    return __uint_as_float(v << 16);
}
__device__ __forceinline__ float bf16_hi(unsigned int v) {
    return __uint_as_float(v & 0xffff0000u);
}
__device__ __forceinline__ unsigned short f2bf(float f) {
    __hip_bfloat16 h = __float2bfloat16(f);   // RNE
    return *(unsigned short*)&h;
}

// ---- prep: zero bcnt/bcur + cast/transpose W0,W1 -> wt[nb][2][128][128] ----
__global__ __launch_bounds__(256) void prep_kernel(
    const float* __restrict__ W0, const float* __restrict__ W1,
    unsigned short* __restrict__ wt, int* __restrict__ bcnt,
    int* __restrict__ bcur, int nb)
{
    int i = blockIdx.x * 256 + threadIdx.x;
    int ncast = nb * 2 * DIM * DIM;            // nb*32768
    if (i < ncast) {
        int w   = i >> 15;
        int rem = i & 32767;
        int m   = rem >> 14;                   // 0:W0 1:W1
        int j   = rem & 16383;
        int n   = j >> 7, k = j & 127;
        const float* Ws = (m ? W1 : W0) + (size_t)w * DIM * DIM;
        wt[i] = f2bf(Ws[k * DIM + n]);         // wt[(w*2+m)*16384 + n*128 + k]
    }
    if (i < nb * NB2) { bcnt[i] = 0; bcur[i] = 0; }
}

// ---- bhist: block-aggregated coarse histogram (<=98 global atomics/block) ----
__global__ __launch_bounds__(256) void bhist_kernel(
    const int* __restrict__ ei, int* __restrict__ bcnt)
{
    const int w = blockIdx.y, b0 = blockIdx.x * EPB;
    const int t = threadIdx.x;
    __shared__ int lh[NB2];
    for (int i = t; i < NB2; i += 256) lh[i] = 0;
    __syncthreads();
    const int* dst = ei + (size_t)w * 2 * NEDGES + NEDGES;
    #pragma unroll
    for (int j = 0; j < EPB / 256; ++j) {
        int e = b0 + j * 256 + t;
        if (e < NEDGES) atomicAdd(&lh[dst[e] >> BSH], 1);
    }
    __syncthreads();
    for (int i = t; i < NB2; i += 256)
        if (lh[i]) atomicAdd(&bcnt[w * NB2 + i], lh[i]);
}

// ---- bscan: exclusive scan of 98 bucket counts (one 128-thr block/window) ----
__global__ __launch_bounds__(128) void bscan_kernel(
    const int* __restrict__ bcnt, int* __restrict__ bbase, int* __restrict__ offs)
{
    const int w = blockIdx.x;
    const int t = threadIdx.x;
    __shared__ int s[128];
    int orig = (t < NB2) ? bcnt[w * NB2 + t] : 0;
    s[t] = orig;
    __syncthreads();
    for (int off = 1; off < 128; off <<= 1) {
        int v = (t >= off) ? s[t - off] : 0;
        __syncthreads();
        s[t] += v;
        __syncthreads();
    }
    if (t < NB2) bbase[w * (NB2 + 1) + t] = s[t] - orig;       // exclusive
    if (t == NB2 - 1) {
        bbase[w * (NB2 + 1) + NB2] = s[t];                     // total == NEDGES
        offs[(size_t)w * (NNODES + 1) + NNODES] = s[t];
    }
}

// ---- bucket_p1: block multi-split. One global atomic per (block,bucket); ----
// ---- each bucket's run written as a contiguous burst by a single block. ----
__global__ __launch_bounds__(256) void bucket_p1(
    const int* __restrict__ ei, const float* __restrict__ ew,
    const int* __restrict__ bbase, int* __restrict__ bcur,
    int2* __restrict__ stage)
{
    const int w = blockIdx.y, b0 = blockIdx.x * EPB;
    const int t = threadIdx.x;
    __shared__ int lh[NB2];
    __shared__ int gb[NB2];
    for (int i = t; i < NB2; i += 256) lh[i] = 0;
    __syncthreads();
    const int*   eiw = ei + (size_t)w * 2 * NEDGES;
    const float* eww = ew + (size_t)w * NEDGES;
    int  tag[EPB / 256];           // (bucket<<12) | local_rank, -1 = invalid
    int2 pk[EPB / 256];
    #pragma unroll
    for (int j = 0; j < EPB / 256; ++j) {
        int e = b0 + j * 256 + t;
        if (e < NEDGES) {
            int d = eiw[NEDGES + e], s = eiw[e];
            int b = d >> BSH;
            int r = atomicAdd(&lh[b], 1);      // local rank within (block,bucket)
            tag[j] = (b << 12) | r;            // r < 4096
            pk[j]  = make_int2(s | ((d & (BSZ - 1)) << 16),
                               __float_as_int(eww[e]));
        } else tag[j] = -1;
    }
    __syncthreads();
    for (int i = t; i < NB2; i += 256)
        gb[i] = bbase[w * (NB2 + 1) + i]
              + (lh[i] ? atomicAdd(&bcur[w * NB2 + i], lh[i]) : 0);
    __syncthreads();
    int2* st = stage + (size_t)w * NEDGES;
    #pragma unroll
    for (int j = 0; j < EPB / 256; ++j) {
        if (tag[j] >= 0)
            st[gb[tag[j] >> 12] + (tag[j] & 4095)] = pk[j];
    }
}

// ---- bucket_p2: per-bucket per-dst sort -> offs[dst] + dst-sorted srcw ----
// One block per (bucket, window): ~4K edges, dense 32KB output (full lines).
// Also produces the per-dst CSR offsets (replaces hist + 3-phase scan).
__global__ __launch_bounds__(256) void bucket_p2(
    const int2* __restrict__ stage, const int* __restrict__ bbase,
    int* __restrict__ offs, int2* __restrict__ srcw)
{
    const int b = blockIdx.x, w = blockIdx.y;
    const int t = threadIdx.x;
    __shared__ int s[BSZ];
    const int base = bbase[w * (NB2 + 1) + b];
    const int n    = bbase[w * (NB2 + 1) + b + 1] - base;
    s[t] = 0; s[t + 256] = 0;
    __syncthreads();
    const int2* st = stage + (size_t)w * NEDGES + base;
    for (int i = t; i < n; i += 256)
        atomicAdd(&s[(st[i].x >> 16) & (BSZ - 1)], 1);
    __syncthreads();
    int o0 = s[t], o1 = s[t + 256];
    // inclusive Hillis-Steele over 512 counters, 2 elems/thread
    for (int off = 1; off < BSZ; off <<= 1) {
        int a0 = (t >= off) ? s[t - off] : 0;
        int a1 = (t + 256 >= off) ? s[t + 256 - off] : 0;
        __syncthreads();
        s[t] += a0; s[t + 256] += a1;
        __syncthreads();
    }
    int c0 = base + s[t] - o0;                 // absolute exclusive prefix
    int c1 = base + s[t + 256] - o1;
    __syncthreads();
    s[t] = c0; s[t + 256] = c1;                // become scatter cursors
    int* ofw = offs + (size_t)w * (NNODES + 1);
    int n0 = b * BSZ + t, n1 = b * BSZ + t + 256;
    if (n0 < NNODES) ofw[n0] = c0;
    if (n1 < NNODES) ofw[n1] = c1;
    __syncthreads();
    int2* sw = srcw + (size_t)w * NEDGES;
    for (int i = t; i < n; i += 256) {
        int2 e = st[i];
        int pos = atomicAdd(&s[(e.x >> 16) & (BSZ - 1)], 1);
        sw[pos] = make_int2(e.x & 0xffff, e.y);
    }
}

// ---- MFMA GEMM (batched): C_bf16[w] = A'[w] @ W[w], A' = elu(A+bias) if bias ----
__global__ __launch_bounds__(256) void gemm_mfma(
    const void* __restrict__ Avoid, size_t a_stride,        // elements per window
    const unsigned short* __restrict__ WtG, size_t wt_stride,
    const float* __restrict__ bias,                          // null or stride DIM
    unsigned short* __restrict__ C,                          // stride N*DIM
    int a_bf16)
{
    __shared__ unsigned short As[BM][136];
    __shared__ unsigned short Bs[DIM][136];
    const int t  = threadIdx.x;
    const int r0 = blockIdx.x * BM;
    const int w  = blockIdx.y;
    const unsigned short* Wt = WtG + (size_t)w * wt_stride;
    unsigned short* Cw = C + (size_t)w * NNODES * DIM;

    if (a_bf16) {
        const unsigned short* A = (const unsigned short*)Avoid + (size_t)w * a_stride;
        const float* bs = bias + (size_t)w * DIM;
        #pragma unroll
        for (int l = 0; l < 4; ++l) {
            int idx = t + l * 256;             // 1024 uint4 = 64x128 bf16
            int row = idx >> 4, c8 = (idx & 15) << 3;
            int gr  = r0 + row;
            uint4 v = make_uint4(0, 0, 0, 0);
            if (gr < NNODES) v = *(const uint4*)(A + (size_t)gr * DIM + c8);
            union { uint4 u; unsigned short s[8]; } in, ot;
            in.u = v;
            #pragma unroll
            for (int j = 0; j < 8; ++j) {
                float f = __uint_as_float((unsigned int)in.s[j] << 16);
                ot.s[j] = f2bf(eluf(f + bs[c8 + j]));
            }
            *(uint4*)&As[row][c8] = ot.u;
        }
    } else {
        const float* A = (const float*)Avoid + (size_t)w * a_stride;
        #pragma unroll
        for (int l = 0; l < 8; ++l) {
            int idx = t + l * 256;             // 2048 float4 = 64x128 fp32
            int row = idx >> 5, c4 = (idx & 31) << 2;
            int gr  = r0 + row;
            float4 v = make_float4(0.f, 0.f, 0.f, 0.f);
            if (gr < NNODES) v = *(const float4*)(A + (size_t)gr * DIM + c4);
            union { uint2 u; unsigned short s[4]; } ot;
            ot.s[0] = f2bf(v.x); ot.s[1] = f2bf(v.y);
            ot.s[2] = f2bf(v.z); ot.s[3] = f2bf(v.w);
            *(uint2*)&As[row][c4] = ot.u;
        }
    }
    // full W^T: 128x128 bf16 = 2048 uint4 chunks
    #pragma unroll
    for (int l = 0; l < 8; ++l) {
        int idx = t + l * 256;
        int n = idx >> 4, k8 = (idx & 15) << 3;
        *(uint4*)&Bs[n][k8] = *(const uint4*)(Wt + (size_t)n * DIM + k8);
    }
    __syncthreads();

    const int lane = t & 63, wv = t >> 6;
    const int mr = lane & 15, quad = lane >> 4;

    f32x4 acc[8];
    #pragma unroll
    for (int c = 0; c < 8; ++c) acc[c] = (f32x4){0.f, 0.f, 0.f, 0.f};

    const unsigned short* aptr = &As[wv * 16 + mr][quad * 8];
    #pragma unroll
    for (int kc = 0; kc < DIM; kc += 32) {
        bf16x8 a = *(const bf16x8*)(aptr + kc);
        #pragma unroll
        for (int c = 0; c < 8; ++c) {
            bf16x8 b = *(const bf16x8*)(&Bs[c * 16 + mr][quad * 8 + kc]);
            acc[c] = __builtin_amdgcn_mfma_f32_16x16x32_bf16(a, b, acc[c], 0, 0, 0);
        }
    }
    // Epilogue: bounce C tile through LDS (reuse As) -> coalesced uint4 stores
    __syncthreads();
    const int lr0 = wv * 16 + quad * 4;
    #pragma unroll
    for (int c = 0; c < 8; ++c) {
        int col = c * 16 + mr;
        #pragma unroll
        for (int r = 0; r < 4; ++r)
            As[lr0 + r][col] = f2bf(acc[c][r]);   // C/D: col=lane&15, row=quad*4+r
    }
    __syncthreads();
    #pragma unroll
    for (int l = 0; l < 4; ++l) {
        int idx = t + l * 256;                 // 1024 = 64 rows x 16 chunks
        int row = idx >> 4, c8 = (idx & 15) << 3;
        int gr = r0 + row;
        if (gr < NNODES)
            *(uint4*)(Cw + (size_t)gr * DIM + c8) = *(const uint4*)&As[row][c8];
    }
}

// ---- gather_agg (batched): one wave per dst, int2 edge stream, 4-wide ILP ----
// mode 0: agg_bf16[w][dst] = sum.  mode 1: out_f32[w][dst] = elu(sum + bias).
__global__ __launch_bounds__(256) void gather_agg(
    const unsigned short* __restrict__ h,
    const int*  __restrict__ offs,
    const int2* __restrict__ srcw,
    const float* __restrict__ bias,
    void* __restrict__ outp,
    int mode)
{
    const int w = blockIdx.y;
    const unsigned short* hw = h + (size_t)w * NNODES * DIM;
    const int*  ow = offs + (size_t)w * (NNODES + 1);
    const int2* sw = srcw + (size_t)w * NEDGES;
    int wid  = (blockIdx.x * 256 + threadIdx.x) >> 6;
    int lane = threadIdx.x & 63;
    if (wid >= NNODES) return;
    int beg = ow[wid], end = ow[wid + 1];
    const int d0 = lane * 2;
    float ax = 0.f, ay = 0.f;

    int e = beg;
    for (; e + 4 <= end; e += 4) {
        int2 p0 = sw[e],     p1 = sw[e + 1];
        int2 p2 = sw[e + 2], p3 = sw[e + 3];
        unsigned int v0 = *(const unsigned int*)(hw + (size_t)p0.x * DIM + d0);
        unsigned int v1 = *(const unsigned int*)(hw + (size_t)p1.x * DIM + d0);
        unsigned int v2 = *(const unsigned int*)(hw + (size_t)p2.x * DIM + d0);
        unsigned int v3 = *(const unsigned int*)(hw + (size_t)p3.x * DIM + d0);
        float w0 = __int_as_float(p0.y), w1 = __int_as_float(p1.y);
        float w2 = __int_as_float(p2.y), w3 = __int_as_float(p3.y);
        ax += w0 * bf16_lo(v0); ay += w0 * bf16_hi(v0);
        ax += w1 * bf16_lo(v1); ay += w1 * bf16_hi(v1);
        ax += w2 * bf16_lo(v2); ay += w2 * bf16_hi(v2);
        ax += w3 * bf16_lo(v3); ay += w3 * bf16_hi(v3);
    }
    for (; e < end; ++e) {
        int2 p = sw[e];
        float wf = __int_as_float(p.y);
        unsigned int v = *(const unsigned int*)(hw + (size_t)p.x * DIM + d0);
        ax += wf * bf16_lo(v); ay += wf * bf16_hi(v);
    }

    if (mode == 0) {
        unsigned int pk = (unsigned int)f2bf(ax) | ((unsigned int)f2bf(ay) << 16);
        *((unsigned int*)outp + (size_t)w * NNODES * (DIM / 2)
                              + (size_t)wid * (DIM / 2) + lane) = pk;
    } else {
        const float* bs = bias + (size_t)w * DIM;
        float2 r;
        r.x = eluf(ax + bs[d0 + 0]);
        r.y = eluf(ay + bs[d0 + 1]);
        *(float2*)((float*)outp + (size_t)w * NNODES * DIM + (size_t)wid * DIM + d0) = r;
    }
}

extern "C" void kernel_launch(void* const* d_in, const int* in_sizes, int n_in,
                              void* d_out, int out_size, void* d_ws, size_t ws_size,
                              hipStream_t stream) {
    const float* x           = (const float*)d_in[0];
    const int*   edge_index  = (const int*)  d_in[1];
    const float* edge_weight = (const float*)d_in[2];
    const float* W0          = (const float*)d_in[3];
    const float* b0          = (const float*)d_in[4];
    const float* W1          = (const float*)d_in[5];
    const float* b1          = (const float*)d_in[6];
    float*       out         = (float*)d_out;

    const size_t ND = (size_t)NNODES * DIM;

    // Workspace per batched-window: h + agg (bf16) + wt + srcw + offs + bucket meta
    auto need = [&](int nb) -> size_t {
        return (size_t)nb * (ND * 2 + ND * 2 + 2 * DIM * DIM * 2
                             + (size_t)NEDGES * 8
                             + (size_t)(NNODES + 1) * 4
                             + (size_t)NB2 * 4 * 2 + (size_t)(NB2 + 1) * 4);
    };
    int nb = WINDOW;
    while (nb > 1 && need(nb) > ws_size) nb >>= 1;

    char* p = (char*)d_ws;
    unsigned short* h_buf   = (unsigned short*)p;  p += (size_t)nb * ND * 2;
    unsigned short* agg_buf = (unsigned short*)p;  p += (size_t)nb * ND * 2;
    unsigned short* wt      = (unsigned short*)p;  p += (size_t)nb * 2 * DIM * DIM * 2;
    int2*           srcw    = (int2*)p;            p += (size_t)nb * NEDGES * 8;
    int*            offs    = (int*)p;             p += (size_t)nb * (NNODES + 1) * 4;
    int*            bcnt    = (int*)p;             p += (size_t)nb * NB2 * 4;
    int*            bcur    = (int*)p;             p += (size_t)nb * NB2 * 4;
    int*            bbase   = (int*)p;             p += (size_t)nb * (NB2 + 1) * 4;
    int2*           stage   = (int2*)h_buf;        // reuse h_buf before gemm hop 1

    const dim3 hg(P1B, nb);                           // multi-split blocks
    const dim3 gg((NNODES + BM - 1) / BM, nb);        // gemm tiles
    const dim3 ag((NNODES * 64 + 255) / 256, nb);     // one wave per dst
    const dim3 bg(NB2, nb);                           // per-bucket pass
    const int  prep_grid = (nb * 2 * DIM * DIM + 255) / 256;

    for (int w0 = 0; w0 < WINDOW; w0 += nb) {
        const float* W0g = W0 + (size_t)w0 * DIM * DIM;
        const float* W1g = W1 + (size_t)w0 * DIM * DIM;
        const int*   eig = edge_index  + (size_t)w0 * 2 * NEDGES;
        const float* ewg = edge_weight + (size_t)w0 * NEDGES;

        prep_kernel <<<prep_grid, 256, 0, stream>>>(W0g, W1g, wt, bcnt, bcur, nb);
        bhist_kernel<<<hg, 256, 0, stream>>>(eig, bcnt);
        bscan_kernel<<<nb, 128, 0, stream>>>(bcnt, bbase, offs);
        bucket_p1   <<<hg, 256, 0, stream>>>(eig, ewg, bbase, bcur, stage);
        bucket_p2   <<<bg, 256, 0, stream>>>(stage, bbase, offs, srcw);

        // hop 1: h = x @ W0 ; agg = gather(h)   (gemm overwrites stage == h_buf)
        gemm_mfma <<<gg, 256, 0, stream>>>(x + (size_t)w0 * ND, ND,
                                           wt, 2 * DIM * DIM, nullptr, h_buf, 0);
        gather_agg<<<ag, 256, 0, stream>>>(h_buf, offs, srcw, nullptr, agg_buf, 0);
        // hop 2: h = elu(agg+b0) @ W1 ; out = elu(gather(h) + b1)
        gemm_mfma <<<gg, 256, 0, stream>>>(agg_buf, ND,
                                           wt + DIM * DIM, 2 * DIM * DIM,
                                           b0 + (size_t)w0 * DIM, h_buf, 1);
        gather_agg<<<ag, 256, 0, stream>>>(h_buf, offs, srcw,
                                           b1 + (size_t)w0 * DIM,
                                           out + (size_t)w0 * ND, 1);
    }
}